// Round 15
// baseline (616.047 us; speedup 1.0000x reference)
//
#include <hip/hip_runtime.h>
#include <hip/hip_bf16.h>

// CapsModel: B=64 N=32 H=W=16 A=16 K=3 stride=2 -> Ho=Wo=7, M=32, SD=4, D=16
// conv routing R15: ONE site per block (3136 x 256 thr = 8 g x 32 m).
//   Routing passes process t in TRIPLES with 3 interleaved softmax butterflies
//   (R14's 2-way interleave -> 318->227us proved the cross-lane chain is the
//   wall; 3 independent chains hide more). Peak live ~76 VGPR < (256,6) cap 85.
// fc routing: pass-split kernels (unchanged from R12).

#define LN_EPS 1e-5f

typedef _Float16 h2 __attribute__((ext_vector_type(2)));

__device__ __forceinline__ unsigned packh2(float a, float b) {
    const unsigned short ua = __builtin_bit_cast(unsigned short, (_Float16)a);
    const unsigned short ub = __builtin_bit_cast(unsigned short, (_Float16)b);
    return (unsigned)ua | ((unsigned)ub << 16);
}

__device__ __forceinline__ float fdot2u(unsigned a, unsigned b, float c) {
#if __has_builtin(__builtin_amdgcn_fdot2)
    return __builtin_amdgcn_fdot2(__builtin_bit_cast(h2, a),
                                  __builtin_bit_cast(h2, b), c, false);
#else
    const h2 ha = __builtin_bit_cast(h2, a), hb = __builtin_bit_cast(h2, b);
    return fmaf((float)ha.x, (float)hb.x, fmaf((float)ha.y, (float)hb.y, c));
#endif
}

// ---------------- weight transposes ----------------
// wTh [288][32][16] f16: row r = n*9+kl; inner idx = d*4+x (x-pairs adjacent).
__global__ __launch_bounds__(256) void transpose_wconv(
    const float* __restrict__ wconv, unsigned short* __restrict__ wTh)
{
    const int i = blockIdx.x * 256 + threadIdx.x;
    if (i < 147456) {
        const int x = i & 3, d = (i >> 2) & 3, mm = (i >> 4) & 31, r = i >> 9;
        const int n = r / 9, kl = r % 9;
        const float v = wconv[((kl * 32 + n) * 16 + x * 4 + d) * 32 + mm];
        wTh[i] = __builtin_bit_cast(unsigned short, (_Float16)v);
    }
}
// wT2b [1568][16][16] fp32: [n][m (pad 10->16, zeros)][x*4+d]
__global__ __launch_bounds__(256) void transpose_wfc(
    const float* __restrict__ wfc, float* __restrict__ wT2b)
{
    const int j = blockIdx.x * 256 + threadIdx.x;
    if (j < 401408) {
        const int xd = j & 15, mm = (j >> 4) & 15, n = j >> 8;
        const int x = xd >> 2, dd = xd & 3;
        wT2b[j] = (mm < 10) ? wfc[((n * 4 + x) * 4 + dd) * 10 + mm] : 0.f;
    }
}
// fused (roomy ws layout)
__global__ __launch_bounds__(256) void transpose_weights(
    const float* __restrict__ wconv, const float* __restrict__ wfc,
    unsigned short* __restrict__ wTh, float* __restrict__ wT2b)
{
    const int blk = blockIdx.x;
    if (blk < 576) {
        const int i = blk * 256 + threadIdx.x;
        if (i < 147456) {
            const int x = i & 3, d = (i >> 2) & 3, mm = (i >> 4) & 31, r = i >> 9;
            const int n = r / 9, kl = r % 9;
            const float v = wconv[((kl * 32 + n) * 16 + x * 4 + d) * 32 + mm];
            wTh[i] = __builtin_bit_cast(unsigned short, (_Float16)v);
        }
    } else {
        const int j = (blk - 576) * 256 + threadIdx.x;
        if (j < 401408) {
            const int xd = j & 15, mm = (j >> 4) & 15, n = j >> 8;
            const int x = xd >> 2, dd = xd & 3;
            wT2b[j] = (mm < 10) ? wfc[((n * 4 + x) * 4 + dd) * 10 + mm] : 0.f;
        }
    }
}

// ---------------- Stage 1: conv routing ----------------
__global__ __launch_bounds__(256, 6) void conv_routing_kernel(
    const float* __restrict__ x,             // [64][32][16][16][16]
    const unsigned short* __restrict__ wTh,  // [288][32][16] f16
    const float* __restrict__ ln1g,
    const float* __restrict__ ln1b,
    const int*   __restrict__ nroute,
    float* __restrict__ vout)                // [64][32][49][16]
{
    __shared__ unsigned short s_inp[288][16];  // f16 x-pairs, 9,216 B
    __shared__ float s_v[32][17];              // 2,176 B
    __shared__ float s_red[2][32][17];         // 4,352 B  => 15,744 B total

    const int tid = threadIdx.x;
    const int m   = tid & 31;
    const int g   = (tid >> 5) & 7;  // 0..7
    const int lw  = tid >> 6;        // 0..3
    const int site = blockIdx.x;
    const int b = site / 49, hw = site % 49;
    const int h = hw / 7, w = hw % 7;

    // stage inp (coalesced float4 loads, f16 pack); row = n*9+kl
    for (int i = tid; i < 1152; i += 256) {    // 288 rows * 4 quads
        const int row = i >> 2, q = i & 3;
        const int n = row / 9, kl = row % 9;
        const int k = kl / 3, l = kl % 3;
        const float4 val = *(const float4*)(
            x + ((((b * 32 + n) * 16 + (2 * h + k)) * 16 + (2 * w + l)) * 16 + q * 4));
        uint2 p;
        p.x = packh2(val.x, val.y);
        p.y = packh2(val.z, val.w);
        *(uint2*)(&s_inp[row][q * 4]) = p;
    }
    __syncthreads();

    const int R = *nroute;
    const int nkl0 = g * 36;
    const unsigned short* const wp0 = wTh + (nkl0 * 32 + m) * 16;

    for (int pass = 0; pass < R; ++pass) {
        float vn[16];
#pragma unroll
        for (int i = 0; i < 16; ++i) vn[i] = 0.f;

        if (pass == 0) {
            const unsigned short* wp = wp0;
            for (int t = 0; t < 36; ++t, wp += 512) {
                const uint4 wa = *(const uint4*)(wp);
                const uint4 wb = *(const uint4*)(wp + 8);
                const unsigned wu[8] = { wa.x, wa.y, wa.z, wa.w, wb.x, wb.y, wb.z, wb.w };
                const uint4* rp = (const uint4*)(&s_inp[nkl0 + t][0]);
                const uint4 ua = rp[0], ub = rp[1];
                const unsigned iu[8] = { ua.x, ua.y, ua.z, ua.w, ub.x, ub.y, ub.z, ub.w };
#pragma unroll
                for (int a = 0; a < 4; ++a) {
#pragma unroll
                    for (int d = 0; d < 4; ++d) {
                        vn[a * 4 + d] = fdot2u(iu[a * 2], wu[d * 2],
                            fdot2u(iu[a * 2 + 1], wu[d * 2 + 1], vn[a * 4 + d]));
                    }
                }
            }
        } else {
            const unsigned short* wp = wp0;
            for (int j = 0; j < 12; ++j, wp += 1536) {   // t-triples
                float uh0[16], uh1[16], uh2[16];
                {
                    const uint4 wa0 = *(const uint4*)(wp);
                    const uint4 wb0 = *(const uint4*)(wp + 8);
                    const uint4 wa1 = *(const uint4*)(wp + 512);
                    const uint4 wb1 = *(const uint4*)(wp + 520);
                    const uint4 wa2 = *(const uint4*)(wp + 1024);
                    const uint4 wb2 = *(const uint4*)(wp + 1032);
                    const unsigned wu0[8] = { wa0.x, wa0.y, wa0.z, wa0.w, wb0.x, wb0.y, wb0.z, wb0.w };
                    const unsigned wu1[8] = { wa1.x, wa1.y, wa1.z, wa1.w, wb1.x, wb1.y, wb1.z, wb1.w };
                    const unsigned wu2[8] = { wa2.x, wa2.y, wa2.z, wa2.w, wb2.x, wb2.y, wb2.z, wb2.w };
                    const uint4* rp0 = (const uint4*)(&s_inp[nkl0 + 3 * j][0]);
                    const uint4* rp1 = (const uint4*)(&s_inp[nkl0 + 3 * j + 1][0]);
                    const uint4* rp2 = (const uint4*)(&s_inp[nkl0 + 3 * j + 2][0]);
                    const uint4 ua0 = rp0[0], ub0 = rp0[1];
                    const uint4 ua1 = rp1[0], ub1 = rp1[1];
                    const uint4 ua2 = rp2[0], ub2 = rp2[1];
                    const unsigned iu0[8] = { ua0.x, ua0.y, ua0.z, ua0.w, ub0.x, ub0.y, ub0.z, ub0.w };
                    const unsigned iu1[8] = { ua1.x, ua1.y, ua1.z, ua1.w, ub1.x, ub1.y, ub1.z, ub1.w };
                    const unsigned iu2[8] = { ua2.x, ua2.y, ua2.z, ua2.w, ub2.x, ub2.y, ub2.z, ub2.w };
#pragma unroll
                    for (int a = 0; a < 4; ++a) {
#pragma unroll
                        for (int d = 0; d < 4; ++d) {
                            uh0[a * 4 + d] = fdot2u(iu0[a * 2], wu0[d * 2],
                                fdot2u(iu0[a * 2 + 1], wu0[d * 2 + 1], 0.f));
                            uh1[a * 4 + d] = fdot2u(iu1[a * 2], wu1[d * 2],
                                fdot2u(iu1[a * 2 + 1], wu1[d * 2 + 1], 0.f));
                            uh2[a * 4 + d] = fdot2u(iu2[a * 2], wu2[d * 2],
                                fdot2u(iu2[a * 2 + 1], wu2[d * 2 + 1], 0.f));
                        }
                    }
                }

                // logits (vc scalar LDS reads, shared across the 3 t's)
                const float* vcp = &s_v[m][0];
                float p0 = 0.f, p1 = 0.f, p2 = 0.f;
                float q0 = 0.f, q1 = 0.f, q2 = 0.f;
#pragma unroll
                for (int i = 0; i < 16; i += 2) {
                    const float c0 = vcp[i], c1 = vcp[i + 1];
                    p0 = fmaf(uh0[i], c0, p0);  q0 = fmaf(uh0[i + 1], c1, q0);
                    p1 = fmaf(uh1[i], c0, p1);  q1 = fmaf(uh1[i + 1], c1, q1);
                    p2 = fmaf(uh2[i], c0, p2);  q2 = fmaf(uh2[i + 1], c1, q2);
                }
                const float e0 = __expf((p0 + q0) * 0.25f);
                const float e1 = __expf((p1 + q1) * 0.25f);
                const float e2 = __expf((p2 + q2) * 0.25f);

                // 3 interleaved butterflies (independent chains)
                float sm0 = e0, sm1 = e1, sm2 = e2;
#pragma unroll
                for (int off = 16; off >= 1; off >>= 1) {
                    const float r0 = __shfl_xor(sm0, off, 32);
                    const float r1 = __shfl_xor(sm1, off, 32);
                    const float r2 = __shfl_xor(sm2, off, 32);
                    sm0 += r0;
                    sm1 += r1;
                    sm2 += r2;
                }
                const float qk0 = e0 * __builtin_amdgcn_rcpf(sm0 * (1.f + 1e-10f));
                const float qk1 = e1 * __builtin_amdgcn_rcpf(sm1 * (1.f + 1e-10f));
                const float qk2 = e2 * __builtin_amdgcn_rcpf(sm2 * (1.f + 1e-10f));
#pragma unroll
                for (int i = 0; i < 16; ++i) {
                    float acc = fmaf(qk0, uh0[i], vn[i]);
                    acc = fmaf(qk1, uh1[i], acc);
                    vn[i] = fmaf(qk2, uh2[i], acc);
                }
            }
        }

        // combine the 2 g's within this wave
#pragma unroll
        for (int i = 0; i < 16; ++i) vn[i] += __shfl_xor(vn[i], 32, 64);

        // 2-stage tree over the 4 waves
        if (lw >= 2) {
#pragma unroll
            for (int i = 0; i < 16; ++i) s_red[lw - 2][m][i] = vn[i];
        }
        __syncthreads();
        if (lw < 2) {
#pragma unroll
            for (int i = 0; i < 16; ++i) vn[i] += s_red[lw][m][i];
            if (lw == 1) {
#pragma unroll
                for (int i = 0; i < 16; ++i) s_red[1][m][i] = vn[i];
            }
        }
        __syncthreads();
        if (lw == 0) {
#pragma unroll
            for (int i = 0; i < 16; ++i) vn[i] += s_red[1][m][i];
            const float scale = pass ? 1.f : (1.f / 32.f);
            float mu = 0.f;
#pragma unroll
            for (int i = 0; i < 16; ++i) { vn[i] *= scale; mu += vn[i]; }
            mu *= (1.f / 16.f);
            float var = 0.f;
#pragma unroll
            for (int i = 0; i < 16; ++i) {
                const float d0 = vn[i] - mu;
                var = fmaf(d0, d0, var);
            }
            var *= (1.f / 16.f);
            const float inv = rsqrtf(var + LN_EPS);
#pragma unroll
            for (int i = 0; i < 16; ++i)
                s_v[m][i] = (vn[i] - mu) * inv * ln1g[i] + ln1b[i];
        }
        __syncthreads();
    }

    // write v (coalesced 16-elem runs)
    for (int p = tid; p < 512; p += 256) {
        const int mm = p >> 4, i = p & 15;
        vout[((b * 32 + mm) * 49 + hw) * 16 + i] = s_v[mm][i];
    }
}

// ---------------- Stage 2: FC routing (pass-split, unchanged) ----------------
__global__ __launch_bounds__(256, 4) void fc_partial(
    const float* __restrict__ fcin,  // [64][1568][16]
    const float* __restrict__ wT2b,  // [1568][16][16] ([n][ml][x*4+d])
    const float* __restrict__ u,     // [64][16][16]
    const int*   __restrict__ nroute,
    const int    pass,
    float* __restrict__ partial)     // [512][16][16]
{
    __shared__ float s_red[4][16][17];

    const int R = *nroute;
    if (pass >= R) return;
    const int blk = blockIdx.x;
    const int b = blk >> 3, c = blk & 7;
    const int tid = threadIdx.x;
    const int ml = tid & 15, grp = tid >> 4;
    const int wv = tid >> 6;
    const float* fb = fcin + (b * 1568 + c * 196) * 16;
    const float* wb = wT2b + (c * 196 * 16) * 16;

    float un[16];
#pragma unroll
    for (int i = 0; i < 16; ++i) un[i] = 0.f;
    float ur[16];
    if (pass) {
#pragma unroll
        for (int q = 0; q < 4; ++q)
            *(float4*)(&ur[q * 4]) = *(const float4*)(u + (b * 16 + ml) * 16 + q * 4);
    }

    for (int t = 0; t < 13; ++t) {
        const int off = t * 16 + grp;
        if (off >= 196) break;
        float iv[16], wv_[16];
        const float* ip = fb + off * 16;
        const float* wp = wb + (off * 16 + ml) * 16;
#pragma unroll
        for (int q = 0; q < 4; ++q) {
            *(float4*)(&iv[q * 4]) = *(const float4*)(ip + q * 4);
            *(float4*)(&wv_[q * 4]) = *(const float4*)(wp + q * 4);
        }
        float vote[16];
#pragma unroll
        for (int a = 0; a < 4; ++a) {
#pragma unroll
            for (int d = 0; d < 4; ++d) {
                float acc = iv[a * 4 + 0] * wv_[0 + d];
                acc = fmaf(iv[a * 4 + 1], wv_[4 + d], acc);
                acc = fmaf(iv[a * 4 + 2], wv_[8 + d], acc);
                acc = fmaf(iv[a * 4 + 3], wv_[12 + d], acc);
                vote[a * 4 + d] = acc;
            }
        }
        if (pass == 0) {
#pragma unroll
            for (int i = 0; i < 16; ++i) un[i] += vote[i];
        } else {
            float l0 = vote[0] * ur[0], l1 = vote[1] * ur[1];
            float l2 = vote[2] * ur[2], l3 = vote[3] * ur[3];
#pragma unroll
            for (int i = 4; i < 16; i += 4) {
                l0 = fmaf(vote[i + 0], ur[i + 0], l0);
                l1 = fmaf(vote[i + 1], ur[i + 1], l1);
                l2 = fmaf(vote[i + 2], ur[i + 2], l2);
                l3 = fmaf(vote[i + 3], ur[i + 3], l3);
            }
            const float lg = ((l0 + l1) + (l2 + l3)) * 0.25f;
            float e = __expf(lg);
            if (ml >= 10) e = 0.f;
            float sm = e;
#pragma unroll
            for (int off2 = 8; off2 >= 1; off2 >>= 1)
                sm += __shfl_xor(sm, off2, 16);
            const float qk = e * __builtin_amdgcn_rcpf(sm * (1.f + 1e-10f));
#pragma unroll
            for (int i = 0; i < 16; ++i) un[i] = fmaf(qk, vote[i], un[i]);
        }
    }

#pragma unroll
    for (int i = 0; i < 16; ++i) {
        un[i] += __shfl_xor(un[i], 16, 64);
        un[i] += __shfl_xor(un[i], 32, 64);
    }
    if ((tid & 63) < 16) {
#pragma unroll
        for (int i = 0; i < 16; ++i) s_red[wv][ml][i] = un[i];
    }
    __syncthreads();
    {
        const int mlf = tid >> 4, i = tid & 15;
        const float s = s_red[0][mlf][i] + s_red[1][mlf][i]
                      + s_red[2][mlf][i] + s_red[3][mlf][i];
        partial[(blk * 16 + mlf) * 16 + i] = s;
    }
}

__global__ __launch_bounds__(256) void fc_combine(
    const float* __restrict__ partial,  // [512][16][16]
    const float* __restrict__ ln2g,
    const float* __restrict__ ln2b,
    const int*   __restrict__ nroute,
    const int    pass,
    float* __restrict__ u,              // [64][16][16]
    float* __restrict__ out)            // [64][10][16]
{
    const int R = *nroute;
    if (pass >= R) return;
    const int b = blockIdx.x;
    const int tid = threadIdx.x;
    const int i = tid & 15, ml = tid >> 4;

    float s = 0.f;
#pragma unroll
    for (int c = 0; c < 8; ++c)
        s += partial[((b * 8 + c) * 16 + ml) * 16 + i];
    if (pass == 0) s *= 0.1f;

    float mu = s;
#pragma unroll
    for (int off = 8; off >= 1; off >>= 1) mu += __shfl_xor(mu, off, 16);
    mu *= (1.f / 16.f);
    const float d0 = s - mu;
    float var = d0 * d0;
#pragma unroll
    for (int off = 8; off >= 1; off >>= 1) var += __shfl_xor(var, off, 16);
    var *= (1.f / 16.f);
    const float r = (s - mu) * rsqrtf(var + LN_EPS) * ln2g[i] + ln2b[i];

    u[(b * 16 + ml) * 16 + i] = r;
    if (pass == R - 1 && ml < 10) out[(b * 10 + ml) * 16 + i] = r;
}

extern "C" void kernel_launch(void* const* d_in, const int* in_sizes, int n_in,
                              void* d_out, int out_size, void* d_ws, size_t ws_size,
                              hipStream_t stream) {
    const float* x     = (const float*)d_in[0];
    const float* wconv = (const float*)d_in[1];
    const float* wfc   = (const float*)d_in[2];
    const float* ln1g  = (const float*)d_in[3];
    const float* ln1b  = (const float*)d_in[4];
    const float* ln2g  = (const float*)d_in[5];
    const float* ln2b  = (const float*)d_in[6];
    const int*   nrt   = (const int*)d_in[7];
    float* out = (float*)d_out;

    float* vout = (float*)d_ws;                                  // 6,422,528 B
    unsigned short* wTh = (unsigned short*)((char*)d_ws + 6422528);  // 294,912 B

    if (ws_size >= 8912896) {
        // roomy layout: wT2b separate -> single fused transpose up front
        float* wT2b    = (float*)((char*)d_ws + 6717440);        // 1,605,632 B
        float* ubuf    = (float*)((char*)d_ws + 8323072);        // 65,536 B
        float* partial = (float*)((char*)d_ws + 8388608);        // 524,288 B

        hipLaunchKernelGGL(transpose_weights, dim3(2144), dim3(256), 0, stream,
                           wconv, wfc, wTh, wT2b);
        hipLaunchKernelGGL(conv_routing_kernel, dim3(3136), dim3(256), 0, stream,
                           x, wTh, ln1g, ln1b, nrt, vout);
        for (int pass = 0; pass < 3; ++pass) {
            hipLaunchKernelGGL(fc_partial, dim3(512), dim3(256), 0, stream,
                               vout, wT2b, ubuf, nrt, pass, partial);
            hipLaunchKernelGGL(fc_combine, dim3(64), dim3(256), 0, stream,
                               partial, ln2g, ln2b, nrt, pass, ubuf, out);
        }
    } else {
        // tight layout: wT2b aliases wTh, sequenced after conv
        float* wT2b    = (float*)((char*)d_ws + 6422528);
        float* ubuf    = (float*)((char*)d_ws + 8028160);        // 65,536 B
        float* partial = (float*)((char*)d_ws + 8093696);        // 524,288 B

        hipLaunchKernelGGL(transpose_wconv, dim3(576), dim3(256), 0, stream,
                           wconv, wTh);
        hipLaunchKernelGGL(conv_routing_kernel, dim3(3136), dim3(256), 0, stream,
                           x, wTh, ln1g, ln1b, nrt, vout);
        hipLaunchKernelGGL(transpose_wfc, dim3(1568), dim3(256), 0, stream,
                           wfc, wT2b);
        for (int pass = 0; pass < 3; ++pass) {
            hipLaunchKernelGGL(fc_partial, dim3(512), dim3(256), 0, stream,
                               vout, wT2b, ubuf, nrt, pass, partial);
            hipLaunchKernelGGL(fc_combine, dim3(64), dim3(256), 0, stream,
                               partial, ln2g, ln2b, nrt, pass, ubuf, out);
        }
    }
}

// Round 16
// 321.534 us; speedup vs baseline: 1.9160x; 1.9160x over previous
//
#include <hip/hip_runtime.h>
#include <hip/hip_bf16.h>

// CapsModel: B=64 N=32 H=W=16 A=16 K=3 stride=2 -> Ho=Wo=7, M=32, SD=4, D=16
// conv routing: EXACT R14 (best validated: 227us). One site per block,
//   3136 x 256 thr, t-PAIRS with 2 interleaved softmax butterflies.
//   (R15's 3-way spilled 1.3GB: compiler pins VGPR=40 under (256,6) and
//   spills whatever doesn't fit. Do not touch.)
// fc routing R16: 4 launches. fc_pass folds the previous pass's combine+LN
//   redundantly into each block (reads prev partial, 8KB); partial double-
//   buffered (pA/pB) to avoid write-after-read races across blocks.
//   pA aliases wTh (dead after conv). Fallback: proven 6-launch path.

#define LN_EPS 1e-5f

typedef _Float16 h2 __attribute__((ext_vector_type(2)));

__device__ __forceinline__ unsigned packh2(float a, float b) {
    const unsigned short ua = __builtin_bit_cast(unsigned short, (_Float16)a);
    const unsigned short ub = __builtin_bit_cast(unsigned short, (_Float16)b);
    return (unsigned)ua | ((unsigned)ub << 16);
}

__device__ __forceinline__ float fdot2u(unsigned a, unsigned b, float c) {
#if __has_builtin(__builtin_amdgcn_fdot2)
    return __builtin_amdgcn_fdot2(__builtin_bit_cast(h2, a),
                                  __builtin_bit_cast(h2, b), c, false);
#else
    const h2 ha = __builtin_bit_cast(h2, a), hb = __builtin_bit_cast(h2, b);
    return fmaf((float)ha.x, (float)hb.x, fmaf((float)ha.y, (float)hb.y, c));
#endif
}

// ---------------- weight transposes ----------------
// wTh [288][32][16] f16: row r = n*9+kl; inner idx = d*4+x (x-pairs adjacent).
__global__ __launch_bounds__(256) void transpose_wconv(
    const float* __restrict__ wconv, unsigned short* __restrict__ wTh)
{
    const int i = blockIdx.x * 256 + threadIdx.x;
    if (i < 147456) {
        const int x = i & 3, d = (i >> 2) & 3, mm = (i >> 4) & 31, r = i >> 9;
        const int n = r / 9, kl = r % 9;
        const float v = wconv[((kl * 32 + n) * 16 + x * 4 + d) * 32 + mm];
        wTh[i] = __builtin_bit_cast(unsigned short, (_Float16)v);
    }
}
// wT2b [1568][16][16] fp32: [n][m (pad 10->16, zeros)][x*4+d]
__global__ __launch_bounds__(256) void transpose_wfc(
    const float* __restrict__ wfc, float* __restrict__ wT2b)
{
    const int j = blockIdx.x * 256 + threadIdx.x;
    if (j < 401408) {
        const int xd = j & 15, mm = (j >> 4) & 15, n = j >> 8;
        const int x = xd >> 2, dd = xd & 3;
        wT2b[j] = (mm < 10) ? wfc[((n * 4 + x) * 4 + dd) * 10 + mm] : 0.f;
    }
}
// fused (roomy ws layout)
__global__ __launch_bounds__(256) void transpose_weights(
    const float* __restrict__ wconv, const float* __restrict__ wfc,
    unsigned short* __restrict__ wTh, float* __restrict__ wT2b)
{
    const int blk = blockIdx.x;
    if (blk < 576) {
        const int i = blk * 256 + threadIdx.x;
        if (i < 147456) {
            const int x = i & 3, d = (i >> 2) & 3, mm = (i >> 4) & 31, r = i >> 9;
            const int n = r / 9, kl = r % 9;
            const float v = wconv[((kl * 32 + n) * 16 + x * 4 + d) * 32 + mm];
            wTh[i] = __builtin_bit_cast(unsigned short, (_Float16)v);
        }
    } else {
        const int j = (blk - 576) * 256 + threadIdx.x;
        if (j < 401408) {
            const int xd = j & 15, mm = (j >> 4) & 15, n = j >> 8;
            const int x = xd >> 2, dd = xd & 3;
            wT2b[j] = (mm < 10) ? wfc[((n * 4 + x) * 4 + dd) * 10 + mm] : 0.f;
        }
    }
}

// ---------------- Stage 1: conv routing (EXACT R14) ----------------
__global__ __launch_bounds__(256, 6) void conv_routing_kernel(
    const float* __restrict__ x,             // [64][32][16][16][16]
    const unsigned short* __restrict__ wTh,  // [288][32][16] f16
    const float* __restrict__ ln1g,
    const float* __restrict__ ln1b,
    const int*   __restrict__ nroute,
    float* __restrict__ vout)                // [64][32][49][16]
{
    __shared__ unsigned short s_inp[288][16];  // f16 x-pairs, 9,216 B
    __shared__ float s_v[32][17];              // 2,176 B
    __shared__ float s_red[2][32][17];         // 4,352 B  => 15,744 B total

    const int tid = threadIdx.x;
    const int m   = tid & 31;
    const int g   = (tid >> 5) & 7;  // 0..7
    const int lw  = tid >> 6;        // 0..3
    const int site = blockIdx.x;
    const int b = site / 49, hw = site % 49;
    const int h = hw / 7, w = hw % 7;

    // stage inp (coalesced float4 loads, f16 pack); row = n*9+kl
    for (int i = tid; i < 1152; i += 256) {    // 288 rows * 4 quads
        const int row = i >> 2, q = i & 3;
        const int n = row / 9, kl = row % 9;
        const int k = kl / 3, l = kl % 3;
        const float4 val = *(const float4*)(
            x + ((((b * 32 + n) * 16 + (2 * h + k)) * 16 + (2 * w + l)) * 16 + q * 4));
        uint2 p;
        p.x = packh2(val.x, val.y);
        p.y = packh2(val.z, val.w);
        *(uint2*)(&s_inp[row][q * 4]) = p;
    }
    __syncthreads();

    const int R = *nroute;
    const int nkl0 = g * 36;
    const unsigned short* const wp0 = wTh + (nkl0 * 32 + m) * 16;

    for (int pass = 0; pass < R; ++pass) {
        float vn[16];
#pragma unroll
        for (int i = 0; i < 16; ++i) vn[i] = 0.f;

        if (pass == 0) {
            const unsigned short* wp = wp0;
            for (int t = 0; t < 36; ++t, wp += 512) {
                const uint4 wa = *(const uint4*)(wp);
                const uint4 wb = *(const uint4*)(wp + 8);
                const unsigned wu[8] = { wa.x, wa.y, wa.z, wa.w, wb.x, wb.y, wb.z, wb.w };
                const uint4* rp = (const uint4*)(&s_inp[nkl0 + t][0]);
                const uint4 ua = rp[0], ub = rp[1];
                const unsigned iu[8] = { ua.x, ua.y, ua.z, ua.w, ub.x, ub.y, ub.z, ub.w };
#pragma unroll
                for (int a = 0; a < 4; ++a) {
#pragma unroll
                    for (int d = 0; d < 4; ++d) {
                        vn[a * 4 + d] = fdot2u(iu[a * 2], wu[d * 2],
                            fdot2u(iu[a * 2 + 1], wu[d * 2 + 1], vn[a * 4 + d]));
                    }
                }
            }
        } else {
            const unsigned short* wp = wp0;
            for (int j = 0; j < 18; ++j, wp += 1024) {   // t-pairs
                const uint4 wa0 = *(const uint4*)(wp);
                const uint4 wb0 = *(const uint4*)(wp + 8);
                const uint4 wa1 = *(const uint4*)(wp + 512);
                const uint4 wb1 = *(const uint4*)(wp + 520);
                const unsigned wu0[8] = { wa0.x, wa0.y, wa0.z, wa0.w, wb0.x, wb0.y, wb0.z, wb0.w };
                const unsigned wu1[8] = { wa1.x, wa1.y, wa1.z, wa1.w, wb1.x, wb1.y, wb1.z, wb1.w };
                const uint4* rp0 = (const uint4*)(&s_inp[nkl0 + 2 * j][0]);
                const uint4* rp1 = (const uint4*)(&s_inp[nkl0 + 2 * j + 1][0]);
                const uint4 ua0 = rp0[0], ub0 = rp0[1];
                const uint4 ua1 = rp1[0], ub1 = rp1[1];
                const unsigned iu0[8] = { ua0.x, ua0.y, ua0.z, ua0.w, ub0.x, ub0.y, ub0.z, ub0.w };
                const unsigned iu1[8] = { ua1.x, ua1.y, ua1.z, ua1.w, ub1.x, ub1.y, ub1.z, ub1.w };

                float uh0[16], uh1[16];
#pragma unroll
                for (int a = 0; a < 4; ++a) {
#pragma unroll
                    for (int d = 0; d < 4; ++d) {
                        uh0[a * 4 + d] = fdot2u(iu0[a * 2], wu0[d * 2],
                            fdot2u(iu0[a * 2 + 1], wu0[d * 2 + 1], 0.f));
                        uh1[a * 4 + d] = fdot2u(iu1[a * 2], wu1[d * 2],
                            fdot2u(iu1[a * 2 + 1], wu1[d * 2 + 1], 0.f));
                    }
                }

                const float* vcp = &s_v[m][0];
                float p0 = 0.f, p1 = 0.f, q0 = 0.f, q1 = 0.f;
#pragma unroll
                for (int i = 0; i < 16; i += 2) {
                    const float c0 = vcp[i], c1 = vcp[i + 1];
                    p0 = fmaf(uh0[i], c0, p0);
                    q0 = fmaf(uh0[i + 1], c1, q0);
                    p1 = fmaf(uh1[i], c0, p1);
                    q1 = fmaf(uh1[i + 1], c1, q1);
                }
                const float e0 = __expf((p0 + q0) * 0.25f);
                const float e1 = __expf((p1 + q1) * 0.25f);

                float sm0 = e0, sm1 = e1;
#pragma unroll
                for (int off = 16; off >= 1; off >>= 1) {
                    const float r0 = __shfl_xor(sm0, off, 32);
                    const float r1 = __shfl_xor(sm1, off, 32);
                    sm0 += r0;
                    sm1 += r1;
                }
                const float qk0 = e0 * __builtin_amdgcn_rcpf(sm0 * (1.f + 1e-10f));
                const float qk1 = e1 * __builtin_amdgcn_rcpf(sm1 * (1.f + 1e-10f));
#pragma unroll
                for (int i = 0; i < 16; ++i) {
                    vn[i] = fmaf(qk0, uh0[i], vn[i]);
                    vn[i] = fmaf(qk1, uh1[i], vn[i]);
                }
            }
        }

#pragma unroll
        for (int i = 0; i < 16; ++i) vn[i] += __shfl_xor(vn[i], 32, 64);

        if (lw >= 2) {
#pragma unroll
            for (int i = 0; i < 16; ++i) s_red[lw - 2][m][i] = vn[i];
        }
        __syncthreads();
        if (lw < 2) {
#pragma unroll
            for (int i = 0; i < 16; ++i) vn[i] += s_red[lw][m][i];
            if (lw == 1) {
#pragma unroll
                for (int i = 0; i < 16; ++i) s_red[1][m][i] = vn[i];
            }
        }
        __syncthreads();
        if (lw == 0) {
#pragma unroll
            for (int i = 0; i < 16; ++i) vn[i] += s_red[1][m][i];
            const float scale = pass ? 1.f : (1.f / 32.f);
            float mu = 0.f;
#pragma unroll
            for (int i = 0; i < 16; ++i) { vn[i] *= scale; mu += vn[i]; }
            mu *= (1.f / 16.f);
            float var = 0.f;
#pragma unroll
            for (int i = 0; i < 16; ++i) {
                const float d0 = vn[i] - mu;
                var = fmaf(d0, d0, var);
            }
            var *= (1.f / 16.f);
            const float inv = rsqrtf(var + LN_EPS);
#pragma unroll
            for (int i = 0; i < 16; ++i)
                s_v[m][i] = (vn[i] - mu) * inv * ln1g[i] + ln1b[i];
        }
        __syncthreads();
    }

    for (int p = tid; p < 512; p += 256) {
        const int mm = p >> 4, i = p & 15;
        vout[((b * 32 + mm) * 49 + hw) * 16 + i] = s_v[mm][i];
    }
}

// ---------------- Stage 2: FC routing ----------------
// fc_pass: 512 blocks = 64 b x 8 chunks; 256 thr = 16 grp x 16 ml.
// For pass>=1, each block redundantly recomputes its b's u from the
// previous pass's partial (combine+LN in LDS) - no ubuf, no extra launch.
__global__ __launch_bounds__(256, 4) void fc_pass(
    const float* __restrict__ fcin,  // [64][1568][16]
    const float* __restrict__ wT2b,  // [1568][16][16] ([n][ml][x*4+d])
    const float* __restrict__ prev,  // [512][16][16] partial from pass-1 (or null)
    const float* __restrict__ ln2g,
    const float* __restrict__ ln2b,
    const int*   __restrict__ nroute,
    const int    pass,
    float* __restrict__ pout)        // [512][16][16]
{
    __shared__ float s_red[4][16][17];
    __shared__ float s_u[16][17];

    const int R = *nroute;
    if (pass >= R) return;
    const int blk = blockIdx.x;
    const int b = blk >> 3, c = blk & 7;
    const int tid = threadIdx.x;
    const int ml = tid & 15, grp = tid >> 4;
    const int wv = tid >> 6;

    float ur[16];
    if (pass) {
        // inline combine + LN: thread (mlf, ii)
        const int mlf = tid >> 4, ii = tid & 15;
        float s = 0.f;
#pragma unroll
        for (int c2 = 0; c2 < 8; ++c2)
            s += prev[((b * 8 + c2) * 16 + mlf) * 16 + ii];
        if (pass == 1) s *= 0.1f;   // pass-0 output carries the 1/Cls scale
        float mu = s;
#pragma unroll
        for (int off = 8; off >= 1; off >>= 1) mu += __shfl_xor(mu, off, 16);
        mu *= (1.f / 16.f);
        const float d0 = s - mu;
        float var = d0 * d0;
#pragma unroll
        for (int off = 8; off >= 1; off >>= 1) var += __shfl_xor(var, off, 16);
        var *= (1.f / 16.f);
        s_u[mlf][ii] = (s - mu) * rsqrtf(var + LN_EPS) * ln2g[ii] + ln2b[ii];
        __syncthreads();
#pragma unroll
        for (int i = 0; i < 16; ++i) ur[i] = s_u[ml][i];
    }

    const float* fb = fcin + (b * 1568 + c * 196) * 16;
    const float* wb = wT2b + (c * 196 * 16) * 16;

    float un[16];
#pragma unroll
    for (int i = 0; i < 16; ++i) un[i] = 0.f;

    for (int t = 0; t < 13; ++t) {
        const int off = t * 16 + grp;
        if (off >= 196) break;
        float iv[16], wv_[16];
        const float* ip = fb + off * 16;
        const float* wp = wb + (off * 16 + ml) * 16;
#pragma unroll
        for (int q = 0; q < 4; ++q) {
            *(float4*)(&iv[q * 4]) = *(const float4*)(ip + q * 4);
            *(float4*)(&wv_[q * 4]) = *(const float4*)(wp + q * 4);
        }
        float vote[16];
#pragma unroll
        for (int a = 0; a < 4; ++a) {
#pragma unroll
            for (int d = 0; d < 4; ++d) {
                float acc = iv[a * 4 + 0] * wv_[0 + d];
                acc = fmaf(iv[a * 4 + 1], wv_[4 + d], acc);
                acc = fmaf(iv[a * 4 + 2], wv_[8 + d], acc);
                acc = fmaf(iv[a * 4 + 3], wv_[12 + d], acc);
                vote[a * 4 + d] = acc;
            }
        }
        if (pass == 0) {
#pragma unroll
            for (int i = 0; i < 16; ++i) un[i] += vote[i];
        } else {
            float l0 = vote[0] * ur[0], l1 = vote[1] * ur[1];
            float l2 = vote[2] * ur[2], l3 = vote[3] * ur[3];
#pragma unroll
            for (int i = 4; i < 16; i += 4) {
                l0 = fmaf(vote[i + 0], ur[i + 0], l0);
                l1 = fmaf(vote[i + 1], ur[i + 1], l1);
                l2 = fmaf(vote[i + 2], ur[i + 2], l2);
                l3 = fmaf(vote[i + 3], ur[i + 3], l3);
            }
            const float lg = ((l0 + l1) + (l2 + l3)) * 0.25f;
            float e = __expf(lg);
            if (ml >= 10) e = 0.f;
            float sm = e;
#pragma unroll
            for (int off2 = 8; off2 >= 1; off2 >>= 1)
                sm += __shfl_xor(sm, off2, 16);
            const float qk = e * __builtin_amdgcn_rcpf(sm * (1.f + 1e-10f));
#pragma unroll
            for (int i = 0; i < 16; ++i) un[i] = fmaf(qk, vote[i], un[i]);
        }
    }

#pragma unroll
    for (int i = 0; i < 16; ++i) {
        un[i] += __shfl_xor(un[i], 16, 64);
        un[i] += __shfl_xor(un[i], 32, 64);
    }
    if ((tid & 63) < 16) {
#pragma unroll
        for (int i = 0; i < 16; ++i) s_red[wv][ml][i] = un[i];
    }
    __syncthreads();
    {
        const int mlf = tid >> 4, i = tid & 15;
        const float s = s_red[0][mlf][i] + s_red[1][mlf][i]
                      + s_red[2][mlf][i] + s_red[3][mlf][i];
        pout[(blk * 16 + mlf) * 16 + i] = s;
    }
}

// fc_final: combine the last pass's partial, LN, write out.
__global__ __launch_bounds__(256) void fc_final(
    const float* __restrict__ pA,    // partial written by even passes
    const float* __restrict__ pB,    // partial written by odd passes
    const float* __restrict__ ln2g,
    const float* __restrict__ ln2b,
    const int*   __restrict__ nroute,
    float* __restrict__ out)         // [64][10][16]
{
    const int R = *nroute;
    const float* P = ((R - 1) & 1) ? pB : pA;
    const int b = blockIdx.x;
    const int tid = threadIdx.x;
    const int i = tid & 15, ml = tid >> 4;

    float s = 0.f;
#pragma unroll
    for (int c = 0; c < 8; ++c)
        s += P[((b * 8 + c) * 16 + ml) * 16 + i];
    if (R == 1) s *= 0.1f;

    float mu = s;
#pragma unroll
    for (int off = 8; off >= 1; off >>= 1) mu += __shfl_xor(mu, off, 16);
    mu *= (1.f / 16.f);
    const float d0 = s - mu;
    float var = d0 * d0;
#pragma unroll
    for (int off = 8; off >= 1; off >>= 1) var += __shfl_xor(var, off, 16);
    var *= (1.f / 16.f);
    const float r = (s - mu) * rsqrtf(var + LN_EPS) * ln2g[i] + ln2b[i];

    if (ml < 10) out[(b * 10 + ml) * 16 + i] = r;
}

// ---------------- fallback 6-launch fc kernels (proven R14 path) ----------------
__global__ __launch_bounds__(256, 4) void fc_partial(
    const float* __restrict__ fcin, const float* __restrict__ wT2b,
    const float* __restrict__ u, const int* __restrict__ nroute,
    const int pass, float* __restrict__ partial)
{
    __shared__ float s_red[4][16][17];
    const int R = *nroute;
    if (pass >= R) return;
    const int blk = blockIdx.x;
    const int b = blk >> 3, c = blk & 7;
    const int tid = threadIdx.x;
    const int ml = tid & 15, grp = tid >> 4;
    const int wv = tid >> 6;
    const float* fb = fcin + (b * 1568 + c * 196) * 16;
    const float* wb = wT2b + (c * 196 * 16) * 16;

    float un[16];
#pragma unroll
    for (int i = 0; i < 16; ++i) un[i] = 0.f;
    float ur[16];
    if (pass) {
#pragma unroll
        for (int q = 0; q < 4; ++q)
            *(float4*)(&ur[q * 4]) = *(const float4*)(u + (b * 16 + ml) * 16 + q * 4);
    }
    for (int t = 0; t < 13; ++t) {
        const int off = t * 16 + grp;
        if (off >= 196) break;
        float iv[16], wv_[16];
        const float* ip = fb + off * 16;
        const float* wp = wb + (off * 16 + ml) * 16;
#pragma unroll
        for (int q = 0; q < 4; ++q) {
            *(float4*)(&iv[q * 4]) = *(const float4*)(ip + q * 4);
            *(float4*)(&wv_[q * 4]) = *(const float4*)(wp + q * 4);
        }
        float vote[16];
#pragma unroll
        for (int a = 0; a < 4; ++a) {
#pragma unroll
            for (int d = 0; d < 4; ++d) {
                float acc = iv[a * 4 + 0] * wv_[0 + d];
                acc = fmaf(iv[a * 4 + 1], wv_[4 + d], acc);
                acc = fmaf(iv[a * 4 + 2], wv_[8 + d], acc);
                acc = fmaf(iv[a * 4 + 3], wv_[12 + d], acc);
                vote[a * 4 + d] = acc;
            }
        }
        if (pass == 0) {
#pragma unroll
            for (int i = 0; i < 16; ++i) un[i] += vote[i];
        } else {
            float l0 = vote[0] * ur[0], l1 = vote[1] * ur[1];
            float l2 = vote[2] * ur[2], l3 = vote[3] * ur[3];
#pragma unroll
            for (int i = 4; i < 16; i += 4) {
                l0 = fmaf(vote[i + 0], ur[i + 0], l0);
                l1 = fmaf(vote[i + 1], ur[i + 1], l1);
                l2 = fmaf(vote[i + 2], ur[i + 2], l2);
                l3 = fmaf(vote[i + 3], ur[i + 3], l3);
            }
            const float lg = ((l0 + l1) + (l2 + l3)) * 0.25f;
            float e = __expf(lg);
            if (ml >= 10) e = 0.f;
            float sm = e;
#pragma unroll
            for (int off2 = 8; off2 >= 1; off2 >>= 1)
                sm += __shfl_xor(sm, off2, 16);
            const float qk = e * __builtin_amdgcn_rcpf(sm * (1.f + 1e-10f));
#pragma unroll
            for (int i = 0; i < 16; ++i) un[i] = fmaf(qk, vote[i], un[i]);
        }
    }
#pragma unroll
    for (int i = 0; i < 16; ++i) {
        un[i] += __shfl_xor(un[i], 16, 64);
        un[i] += __shfl_xor(un[i], 32, 64);
    }
    if ((tid & 63) < 16) {
#pragma unroll
        for (int i = 0; i < 16; ++i) s_red[wv][ml][i] = un[i];
    }
    __syncthreads();
    {
        const int mlf = tid >> 4, i = tid & 15;
        const float s = s_red[0][mlf][i] + s_red[1][mlf][i]
                      + s_red[2][mlf][i] + s_red[3][mlf][i];
        partial[(blk * 16 + mlf) * 16 + i] = s;
    }
}

__global__ __launch_bounds__(256) void fc_combine(
    const float* __restrict__ partial, const float* __restrict__ ln2g,
    const float* __restrict__ ln2b, const int* __restrict__ nroute,
    const int pass, float* __restrict__ u, float* __restrict__ out)
{
    const int R = *nroute;
    if (pass >= R) return;
    const int b = blockIdx.x;
    const int tid = threadIdx.x;
    const int i = tid & 15, ml = tid >> 4;
    float s = 0.f;
#pragma unroll
    for (int c = 0; c < 8; ++c)
        s += partial[((b * 8 + c) * 16 + ml) * 16 + i];
    if (pass == 0) s *= 0.1f;
    float mu = s;
#pragma unroll
    for (int off = 8; off >= 1; off >>= 1) mu += __shfl_xor(mu, off, 16);
    mu *= (1.f / 16.f);
    const float d0 = s - mu;
    float var = d0 * d0;
#pragma unroll
    for (int off = 8; off >= 1; off >>= 1) var += __shfl_xor(var, off, 16);
    var *= (1.f / 16.f);
    const float r = (s - mu) * rsqrtf(var + LN_EPS) * ln2g[i] + ln2b[i];
    u[(b * 16 + ml) * 16 + i] = r;
    if (pass == R - 1 && ml < 10) out[(b * 10 + ml) * 16 + i] = r;
}

extern "C" void kernel_launch(void* const* d_in, const int* in_sizes, int n_in,
                              void* d_out, int out_size, void* d_ws, size_t ws_size,
                              hipStream_t stream) {
    const float* x     = (const float*)d_in[0];
    const float* wconv = (const float*)d_in[1];
    const float* wfc   = (const float*)d_in[2];
    const float* ln1g  = (const float*)d_in[3];
    const float* ln1b  = (const float*)d_in[4];
    const float* ln2g  = (const float*)d_in[5];
    const float* ln2b  = (const float*)d_in[6];
    const int*   nrt   = (const int*)d_in[7];
    float* out = (float*)d_out;

    float* vout = (float*)d_ws;                                  // 6,422,528 B

    if (ws_size >= 9076736) {
        // new layout: wT2b | pA (wTh aliases its head; dead after conv) | pB
        float* wT2b = (float*)((char*)d_ws + 6422528);           // 1,605,632 B
        float* pA   = (float*)((char*)d_ws + 8028160);           // 524,288 B
        float* pB   = (float*)((char*)d_ws + 8552448);           // 524,288 B
        unsigned short* wTh = (unsigned short*)pA;               // 294,912 B alias

        hipLaunchKernelGGL(transpose_weights, dim3(2144), dim3(256), 0, stream,
                           wconv, wfc, wTh, wT2b);
        hipLaunchKernelGGL(conv_routing_kernel, dim3(3136), dim3(256), 0, stream,
                           x, wTh, ln1g, ln1b, nrt, vout);
        hipLaunchKernelGGL(fc_pass, dim3(512), dim3(256), 0, stream,
                           vout, wT2b, (const float*)nullptr, ln2g, ln2b, nrt, 0, pA);
        hipLaunchKernelGGL(fc_pass, dim3(512), dim3(256), 0, stream,
                           vout, wT2b, (const float*)pA, ln2g, ln2b, nrt, 1, pB);
        hipLaunchKernelGGL(fc_pass, dim3(512), dim3(256), 0, stream,
                           vout, wT2b, (const float*)pB, ln2g, ln2b, nrt, 2, pA);
        hipLaunchKernelGGL(fc_final, dim3(64), dim3(256), 0, stream,
                           pA, pB, ln2g, ln2b, nrt, out);
    } else {
        // fallback: R14's proven tight layout, 6-launch fc
        unsigned short* wTh = (unsigned short*)((char*)d_ws + 6422528);
        float* wT2b    = (float*)((char*)d_ws + 6422528);        // aliases wTh
        float* ubuf    = (float*)((char*)d_ws + 8028160);        // 65,536 B
        float* partial = (float*)((char*)d_ws + 8093696);        // 524,288 B

        hipLaunchKernelGGL(transpose_wconv, dim3(576), dim3(256), 0, stream,
                           wconv, wTh);
        hipLaunchKernelGGL(conv_routing_kernel, dim3(3136), dim3(256), 0, stream,
                           x, wTh, ln1g, ln1b, nrt, vout);
        hipLaunchKernelGGL(transpose_wfc, dim3(1568), dim3(256), 0, stream,
                           wfc, wT2b);
        for (int pass = 0; pass < 3; ++pass) {
            hipLaunchKernelGGL(fc_partial, dim3(512), dim3(256), 0, stream,
                               vout, wT2b, ubuf, nrt, pass, partial);
            hipLaunchKernelGGL(fc_combine, dim3(64), dim3(256), 0, stream,
                               partial, ln2g, ln2b, nrt, pass, ubuf, out);
        }
    }
}